// Round 4
// baseline (126.804 us; speedup 1.0000x reference)
//
#include <hip/hip_runtime.h>
#include <hip/hip_bf16.h>

typedef __attribute__((ext_vector_type(8))) short short8;
typedef __attribute__((ext_vector_type(4))) short short4v;
typedef __attribute__((ext_vector_type(4))) float f32x4;
typedef __attribute__((ext_vector_type(8))) __bf16 bf16x8;

#define BB 8
#define CC 64
#define NN 65536        // H*W = 256*256
#define SPLIT1 64       // k1 blocks per batch (512 total = 2 blocks/CU)
#define COLS1 (NN / SPLIT1)   // 1024 cols per k1 block
#define TILE_N 256
#define NT1 (COLS1 / TILE_N)  // 4 tiles per k1 block
#define SPLIT3 128      // k3 blocks per batch (512 cols each)

__device__ inline short f2bf(float f) {
    __hip_bfloat16 h = __float2bfloat16(f);
    return __builtin_bit_cast(short, h);
}

// --- MFMA wrapper: tolerate either short8 or bf16x8 builtin signature ---
template <typename V>
__device__ inline auto mfma_bf16_impl(V a, V b, f32x4 c, int)
    -> decltype(__builtin_amdgcn_mfma_f32_16x16x32_bf16(a, b, c, 0, 0, 0)) {
    return __builtin_amdgcn_mfma_f32_16x16x32_bf16(a, b, c, 0, 0, 0);
}
template <typename V>
__device__ inline f32x4 mfma_bf16_impl(V a, V b, f32x4 c, long) {
    bf16x8 a2 = __builtin_bit_cast(bf16x8, a);
    bf16x8 b2 = __builtin_bit_cast(bf16x8, b);
    return __builtin_amdgcn_mfma_f32_16x16x32_bf16(a2, b2, c, 0, 0, 0);
}
__device__ inline f32x4 mfma16(short8 a, short8 b, f32x4 c) {
    return mfma_bf16_impl(a, b, c, 0);
}

// ------- Kernel 1: partial Gram (bf16 MFMA, double-buffered) + channel sums --
__global__ __launch_bounds__(256, 2) void k1_gram(const float* __restrict__ x,
                                                  float* __restrict__ partialG,
                                                  float* __restrict__ partialS) {
    __shared__ unsigned short tile[2][CC * TILE_N];   // 2 x 32 KB, XOR-swizzled
    const int blk  = blockIdx.x;
    const int b    = blk / SPLIT1;
    const int s    = blk % SPLIT1;
    const int tid  = threadIdx.x;
    const int w    = tid >> 6;       // wave 0..3
    const int lane = tid & 63;
    const int lg   = lane >> 4;      // lane group 0..3
    const int lr   = lane & 15;

    f32x4 acc[4];
#pragma unroll
    for (int dt = 0; dt < 4; ++dt) acc[dt] = (f32x4){0.f, 0.f, 0.f, 0.f};
    float sums[16];
#pragma unroll
    for (int r = 0; r < 16; ++r) sums[r] = 0.f;

    const int colbase0 = s * COLS1;
    float4 pf[16];

    // ---- prologue: load + convert tile 0 ----
#pragma unroll
    for (int r = 0; r < 16; ++r)
        pf[r] = *reinterpret_cast<const float4*>(
            x + ((size_t)(b * CC + w * 16 + r)) * NN + colbase0 + lane * 4);
#pragma unroll
    for (int r = 0; r < 16; ++r) {
        const int row = w * 16 + r;
        const float4 v = pf[r];
        sums[r] += v.x + v.y + v.z + v.w;
        short4v sv;
        sv.x = f2bf(v.x); sv.y = f2bf(v.y); sv.z = f2bf(v.z); sv.w = f2bf(v.w);
        const int idx = ((row << 8) + lane * 4) ^ ((row & 7) << 3);
        *reinterpret_cast<short4v*>(&tile[0][idx]) = sv;
    }
    __syncthreads();

    for (int it = 0; it < NT1; ++it) {
        const int cur = it & 1;
        // ---- issue next tile's global loads (hide HBM latency under MFMA) ----
        if (it + 1 < NT1) {
            const int colbase = colbase0 + (it + 1) * TILE_N;
#pragma unroll
            for (int r = 0; r < 16; ++r)
                pf[r] = *reinterpret_cast<const float4*>(
                    x + ((size_t)(b * CC + w * 16 + r)) * NN + colbase + lane * 4);
        }
        // ---- MFMA on current tile: wave w computes G[w-strip][dt-strip] ----
#pragma unroll
        for (int kk = 0; kk < TILE_N / 32; ++kk) {
            const int col = kk * 32 + lg * 8;
            const int ra  = w * 16 + lr;
            const int ia  = ((ra << 8) + col) ^ ((ra & 7) << 3);
            const short8 af = *reinterpret_cast<const short8*>(&tile[cur][ia]);
#pragma unroll
            for (int dt = 0; dt < 4; ++dt) {
                const int rb = dt * 16 + lr;
                const int ib = ((rb << 8) + col) ^ ((rb & 7) << 3);
                const short8 bf = *reinterpret_cast<const short8*>(&tile[cur][ib]);
                acc[dt] = mfma16(af, bf, acc[dt]);
            }
        }
        // ---- convert + stage next tile into the other LDS buffer ----
        if (it + 1 < NT1) {
#pragma unroll
            for (int r = 0; r < 16; ++r) {
                const int row = w * 16 + r;
                const float4 v = pf[r];
                sums[r] += v.x + v.y + v.z + v.w;
                short4v sv;
                sv.x = f2bf(v.x); sv.y = f2bf(v.y); sv.z = f2bf(v.z); sv.w = f2bf(v.w);
                const int idx = ((row << 8) + lane * 4) ^ ((row & 7) << 3);
                *reinterpret_cast<short4v*>(&tile[cur ^ 1][idx]) = sv;
            }
        }
        __syncthreads();
    }
    // ---- write partial Gram (C/D map: col=lane&15, row=(lane>>4)*4+reg) ----
#pragma unroll
    for (int dt = 0; dt < 4; ++dt) {
#pragma unroll
        for (int r = 0; r < 4; ++r) {
            const int c = w * 16 + lg * 4 + r;
            const int d = dt * 16 + lr;
            partialG[(size_t)blk * 4096 + c * 64 + d] = acc[dt][r];
        }
    }
    // ---- reduce per-row sums across the wave ----
#pragma unroll
    for (int r = 0; r < 16; ++r) {
        float v = sums[r];
        for (int off = 32; off > 0; off >>= 1) v += __shfl_down(v, off);
        if (lane == 0) partialS[blk * CC + w * 16 + r] = v;
    }
}

// ------- Kernel 2 (fused): reduce partials, energy, softmax -> att + offs ---
__global__ __launch_bounds__(256) void k2_fused(const float* __restrict__ partialG,
                                                const float* __restrict__ partialS,
                                                unsigned short* __restrict__ att,
                                                float* __restrict__ offs) {
    __shared__ float mu[CC];
    __shared__ float ener[CC * CC];   // holds G/n
    const int b = blockIdx.x;
    const int tid = threadIdx.x;

    // ---- channel means ----
    if (tid < CC) {
        float s = 0.f;
        for (int sp = 0; sp < SPLIT1; ++sp) s += partialS[(b * SPLIT1 + sp) * CC + tid];
        mu[tid] = s * (1.f / NN);
    }
    // ---- reduce partial Gram: 4 independent f32x4 chains, coalesced ----
    f32x4 sg[4];
#pragma unroll
    for (int p = 0; p < 4; ++p) sg[p] = (f32x4){0.f, 0.f, 0.f, 0.f};
    for (int sp = 0; sp < SPLIT1; ++sp) {
        const f32x4* base = reinterpret_cast<const f32x4*>(
            partialG + (((size_t)(b * SPLIT1 + sp)) << 12));
#pragma unroll
        for (int p = 0; p < 4; ++p) sg[p] += base[tid + p * 256];
    }
    const float inv_n = 1.f / NN;
#pragma unroll
    for (int p = 0; p < 4; ++p) {
        f32x4 v = sg[p];
        v[0] *= inv_n; v[1] *= inv_n; v[2] *= inv_n; v[3] *= inv_n;
        *reinterpret_cast<f32x4*>(&ener[(tid + p * 256) * 4]) = v;
    }
    __syncthreads();

    // ---- softmax rows (mean-center folded in at read) ----
    const int w = tid >> 6, lane = tid & 63;
    for (int i = 0; i < 16; ++i) {
        const int c = w * 16 + i;
        const float v = ener[c * 64 + lane] - mu[c] * mu[lane];
        float m = v;
        for (int off = 32; off > 0; off >>= 1) m = fmaxf(m, __shfl_xor(m, off));
        const float ev = __expf(v - m);
        float sum = ev;
        for (int off = 32; off > 0; off >>= 1) sum += __shfl_xor(sum, off);
        const float a = ev / sum;
        att[(b << 12) + c * 64 + lane] = (unsigned short)f2bf(a);
        float o = a * mu[lane];
        for (int off = 32; off > 0; off >>= 1) o += __shfl_xor(o, off);
        if (lane == 0) offs[b * CC + c] = o;
    }
}

// ---------------- Kernel 3: out = gamma * (A @ x - offset) ------------------
// Non-temporal stores: keep x resident in Infinity Cache.
__global__ __launch_bounds__(256) void k3_apply(const float* __restrict__ x,
                                                const unsigned short* __restrict__ att,
                                                const float* __restrict__ offs,
                                                const float* __restrict__ gamma,
                                                float* __restrict__ out) {
    const int blk  = blockIdx.x;
    const int b    = blk / SPLIT3;
    const int s    = blk % SPLIT3;
    const int tid  = threadIdx.x;
    const int w    = tid >> 6, lane = tid & 63, lg = lane >> 4, lr = lane & 15;
    const float g  = gamma[0];

    // preload attention A-fragments
    short8 afr[4][2];
#pragma unroll
    for (int ct = 0; ct < 4; ++ct)
#pragma unroll
        for (int ks = 0; ks < 2; ++ks)
            afr[ct][ks] = *reinterpret_cast<const short8*>(
                att + (((size_t)b) << 12) + (ct * 16 + lr) * 64 + ks * 32 + lg * 8);

    float offv[4][4];
#pragma unroll
    for (int ct = 0; ct < 4; ++ct)
#pragma unroll
        for (int r = 0; r < 4; ++r)
            offv[ct][r] = offs[b * CC + ct * 16 + lg * 4 + r];

    const int colblock = s * (NN / SPLIT3);
    const int GROUPS = (NN / SPLIT3) / (4 * 64);   // 64-col groups per wave
    for (int itg = 0; itg < GROUPS; ++itg) {
        const int n0 = colblock + (w * GROUPS + itg) * 64;
        f32x4 acc[4][4];   // [phase][ct]
#pragma unroll
        for (int ph = 0; ph < 4; ++ph)
#pragma unroll
            for (int ct = 0; ct < 4; ++ct) acc[ph][ct] = (f32x4){0.f, 0.f, 0.f, 0.f};

#pragma unroll
        for (int ks = 0; ks < 2; ++ks) {
            short8 bfr[4];
            const int d0 = ks * 32 + lg * 8;
            const float* xp = x + ((size_t)(b * CC + d0)) * NN + n0 + lr * 4;
#pragma unroll
            for (int j = 0; j < 8; ++j) {
                const float4 v = *reinterpret_cast<const float4*>(xp + (size_t)j * NN);
                bfr[0][j] = f2bf(v.x);
                bfr[1][j] = f2bf(v.y);
                bfr[2][j] = f2bf(v.z);
                bfr[3][j] = f2bf(v.w);
            }
#pragma unroll
            for (int ct = 0; ct < 4; ++ct) {
#pragma unroll
                for (int ph = 0; ph < 4; ++ph)
                    acc[ph][ct] = mfma16(afr[ct][ks], bfr[ph], acc[ph][ct]);
            }
        }
        // store: row c, cols n0 + lr*4 + {0..3}  (non-temporal, ext-vector type)
#pragma unroll
        for (int ct = 0; ct < 4; ++ct) {
#pragma unroll
            for (int r = 0; r < 4; ++r) {
                const int c = ct * 16 + lg * 4 + r;
                const float o = offv[ct][r];
                f32x4 vs;
                vs[0] = g * (acc[0][ct][r] - o);
                vs[1] = g * (acc[1][ct][r] - o);
                vs[2] = g * (acc[2][ct][r] - o);
                vs[3] = g * (acc[3][ct][r] - o);
                __builtin_nontemporal_store(
                    vs, reinterpret_cast<f32x4*>(out + ((size_t)(b * CC + c)) * NN + n0 + lr * 4));
            }
        }
    }
}

extern "C" void kernel_launch(void* const* d_in, const int* in_sizes, int n_in,
                              void* d_out, int out_size, void* d_ws, size_t ws_size,
                              hipStream_t stream) {
    const float* x     = (const float*)d_in[0];
    const float* gamma = (const float*)d_in[1];
    float* out = (float*)d_out;

    // Large deterministic partials live at the FRONT of d_out (fully overwritten
    // by k3 afterwards). Only the small att/offs tables (read by k3) use d_ws.
    float* partialG = out;                                   // 8*64*4096 floats (8.4 MB)
    float* partialS = out + (size_t)BB * SPLIT1 * 4096;      // 8*64*64 floats
    float* offs     = (float*)d_ws;                          // 512 floats
    unsigned short* att = (unsigned short*)((char*)d_ws + 4096);  // 8*4096 bf16

    k1_gram<<<BB * SPLIT1, 256, 0, stream>>>(x, partialG, partialS);
    k2_fused<<<BB, 256, 0, stream>>>(partialG, partialS, att, offs);
    k3_apply<<<BB * SPLIT3, 256, 0, stream>>>(x, att, offs, gamma, out);
}

// Round 5
// 107.591 us; speedup vs baseline: 1.1786x; 1.1786x over previous
//
#include <hip/hip_runtime.h>
#include <hip/hip_bf16.h>

typedef __attribute__((ext_vector_type(8))) short short8;
typedef __attribute__((ext_vector_type(4))) short short4v;
typedef __attribute__((ext_vector_type(4))) float f32x4;
typedef __attribute__((ext_vector_type(8))) __bf16 bf16x8;

#define BB 8
#define CC 64
#define NN 65536        // H*W = 256*256
#define SPLIT1 128      // k1 blocks per batch (1024 total = 4 blocks/CU)
#define COLS1 (NN / SPLIT1)   // 512 cols per k1 block
#define TILE_N 256
#define SPLIT3 256      // k3 blocks per batch (256 cols each; 2048 blocks total)

__device__ inline short f2bf(float f) {
    __hip_bfloat16 h = __float2bfloat16(f);
    return __builtin_bit_cast(short, h);
}

// --- MFMA wrapper: tolerate either short8 or bf16x8 builtin signature ---
template <typename V>
__device__ inline auto mfma_bf16_impl(V a, V b, f32x4 c, int)
    -> decltype(__builtin_amdgcn_mfma_f32_16x16x32_bf16(a, b, c, 0, 0, 0)) {
    return __builtin_amdgcn_mfma_f32_16x16x32_bf16(a, b, c, 0, 0, 0);
}
template <typename V>
__device__ inline f32x4 mfma_bf16_impl(V a, V b, f32x4 c, long) {
    bf16x8 a2 = __builtin_bit_cast(bf16x8, a);
    bf16x8 b2 = __builtin_bit_cast(bf16x8, b);
    return __builtin_amdgcn_mfma_f32_16x16x32_bf16(a2, b2, c, 0, 0, 0);
}
__device__ inline f32x4 mfma16(short8 a, short8 b, f32x4 c) {
    return mfma_bf16_impl(a, b, c, 0);
}

// ---------------- Kernel 1: partial Gram (bf16 MFMA) + partial channel sums --
// Single-buffered on purpose: the register-prefetch double-buffer variant
// spilled pf[16] to scratch (R4: +66 MB scratch writes, 128 µs). Latency is
// hidden by 4 resident blocks/CU instead.
__global__ __launch_bounds__(256) void k1_gram(const float* __restrict__ x,
                                               float* __restrict__ partialG,
                                               float* __restrict__ partialS) {
    __shared__ unsigned short tile[CC * TILE_N];   // 32 KB, XOR-swizzled
    const int blk  = blockIdx.x;
    const int b    = blk / SPLIT1;
    const int s    = blk % SPLIT1;
    const int tid  = threadIdx.x;
    const int w    = tid >> 6;       // wave 0..3
    const int lane = tid & 63;
    const int lg   = lane >> 4;      // lane group 0..3
    const int lr   = lane & 15;

    f32x4 acc[4];
#pragma unroll
    for (int dt = 0; dt < 4; ++dt) acc[dt] = (f32x4){0.f, 0.f, 0.f, 0.f};
    float sums[16];
#pragma unroll
    for (int r = 0; r < 16; ++r) sums[r] = 0.f;

    const int colbase0 = s * COLS1;

    for (int it = 0; it < COLS1 / TILE_N; ++it) {
        const int colbase = colbase0 + it * TILE_N;
        // ---- load 64 x 256 fp32 -> bf16 LDS tile (coalesced float4) ----
#pragma unroll
        for (int r = 0; r < 16; ++r) {
            const int row = w * 16 + r;
            const float4 v = *reinterpret_cast<const float4*>(
                x + ((size_t)(b * CC + row)) * NN + colbase + lane * 4);
            sums[r] += v.x + v.y + v.z + v.w;
            short4v sv;
            sv.x = f2bf(v.x); sv.y = f2bf(v.y); sv.z = f2bf(v.z); sv.w = f2bf(v.w);
            const int idx = ((row << 8) + lane * 4) ^ ((row & 7) << 3);
            *reinterpret_cast<short4v*>(&tile[idx]) = sv;
        }
        __syncthreads();
        // ---- MFMA: wave w computes G[w-strip][dt-strip] over K=256 ----
#pragma unroll
        for (int kk = 0; kk < TILE_N / 32; ++kk) {
            const int col = kk * 32 + lg * 8;
            const int ra  = w * 16 + lr;
            const int ia  = ((ra << 8) + col) ^ ((ra & 7) << 3);
            const short8 af = *reinterpret_cast<const short8*>(&tile[ia]);
#pragma unroll
            for (int dt = 0; dt < 4; ++dt) {
                const int rb = dt * 16 + lr;
                const int ib = ((rb << 8) + col) ^ ((rb & 7) << 3);
                const short8 bf = *reinterpret_cast<const short8*>(&tile[ib]);
                acc[dt] = mfma16(af, bf, acc[dt]);
            }
        }
        __syncthreads();
    }
    // ---- write partial Gram (C/D map: col=lane&15, row=(lane>>4)*4+reg) ----
#pragma unroll
    for (int dt = 0; dt < 4; ++dt) {
#pragma unroll
        for (int r = 0; r < 4; ++r) {
            const int c = w * 16 + lg * 4 + r;
            const int d = dt * 16 + lr;
            partialG[(size_t)blk * 4096 + c * 64 + d] = acc[dt][r];
        }
    }
    // ---- reduce per-row sums across the wave ----
#pragma unroll
    for (int r = 0; r < 16; ++r) {
        float v = sums[r];
        for (int off = 32; off > 0; off >>= 1) v += __shfl_down(v, off);
        if (lane == 0) partialS[blk * CC + w * 16 + r] = v;
    }
}

// ---------------- Kernel 2a: reduce partial Gram over splits ----------------
// 128 blocks (NOT fused into the 8-block softmax kernel: 8 CUs pulling 16.8 MB
// was a ~20-40 us serial bottleneck in R4).
__global__ __launch_bounds__(256) void k2a_reduceG(const float* __restrict__ partialG,
                                                   float* __restrict__ Gsum) {
    const int gid = blockIdx.x * 256 + threadIdx.x;   // 0..32767
    const int b = gid >> 12;
    const int e = gid & 4095;
    float s = 0.f;
    for (int sp = 0; sp < SPLIT1; ++sp)
        s += partialG[(((size_t)(b * SPLIT1 + sp)) << 12) + e];
    Gsum[gid] = s;
}

// ------- Kernel 2b: means, energy, softmax -> att(bf16) + offsets -----------
__global__ __launch_bounds__(256) void k2b_softmax(const float* __restrict__ partialS,
                                                   const float* __restrict__ Gsum,
                                                   unsigned short* __restrict__ att,
                                                   float* __restrict__ offs) {
    __shared__ float mu[CC];
    __shared__ float ener[CC * CC];
    const int b = blockIdx.x;
    const int tid = threadIdx.x;
    if (tid < CC) {
        float s = 0.f;
        for (int sp = 0; sp < SPLIT1; ++sp) s += partialS[(b * SPLIT1 + sp) * CC + tid];
        mu[tid] = s * (1.f / NN);
    }
    __syncthreads();
    const float inv_n = 1.f / NN;
#pragma unroll
    for (int k = 0; k < 16; ++k) {
        const int e = tid + k * 256;
        const int c = e >> 6, d = e & 63;
        ener[e] = Gsum[(b << 12) + e] * inv_n - mu[c] * mu[d];
    }
    __syncthreads();
    const int w = tid >> 6, lane = tid & 63;
    for (int i = 0; i < 16; ++i) {
        const int c = w * 16 + i;
        const float v = ener[c * 64 + lane];
        float m = v;
        for (int off = 32; off > 0; off >>= 1) m = fmaxf(m, __shfl_xor(m, off));
        const float ev = __expf(v - m);
        float sum = ev;
        for (int off = 32; off > 0; off >>= 1) sum += __shfl_xor(sum, off);
        const float a = ev / sum;
        att[(b << 12) + c * 64 + lane] = (unsigned short)f2bf(a);
        float o = a * mu[lane];
        for (int off = 32; off > 0; off >>= 1) o += __shfl_xor(o, off);
        if (lane == 0) offs[b * CC + c] = o;
    }
}

// ---------------- Kernel 3: out = gamma * (A @ x - offset) ------------------
// Non-temporal stores keep x resident in Infinity Cache (134 MB < 256 MB L3).
// SPLIT3=256 -> 2048 blocks so >2 blocks/CU can be resident for latency hiding.
__global__ __launch_bounds__(256) void k3_apply(const float* __restrict__ x,
                                                const unsigned short* __restrict__ att,
                                                const float* __restrict__ offs,
                                                const float* __restrict__ gamma,
                                                float* __restrict__ out) {
    const int blk  = blockIdx.x;
    const int b    = blk / SPLIT3;
    const int s    = blk % SPLIT3;
    const int tid  = threadIdx.x;
    const int w    = tid >> 6, lane = tid & 63, lg = lane >> 4, lr = lane & 15;
    const float g  = gamma[0];

    // preload attention A-fragments
    short8 afr[4][2];
#pragma unroll
    for (int ct = 0; ct < 4; ++ct)
#pragma unroll
        for (int ks = 0; ks < 2; ++ks)
            afr[ct][ks] = *reinterpret_cast<const short8*>(
                att + (((size_t)b) << 12) + (ct * 16 + lr) * 64 + ks * 32 + lg * 8);

    float offv[4][4];
#pragma unroll
    for (int ct = 0; ct < 4; ++ct)
#pragma unroll
        for (int r = 0; r < 4; ++r)
            offv[ct][r] = offs[b * CC + ct * 16 + lg * 4 + r];

    const int colblock = s * (NN / SPLIT3);
    const int GROUPS = (NN / SPLIT3) / (4 * 64);   // 64-col groups per wave (=1)
    for (int itg = 0; itg < GROUPS; ++itg) {
        const int n0 = colblock + (w * GROUPS + itg) * 64;
        f32x4 acc[4][4];   // [phase][ct]
#pragma unroll
        for (int ph = 0; ph < 4; ++ph)
#pragma unroll
            for (int ct = 0; ct < 4; ++ct) acc[ph][ct] = (f32x4){0.f, 0.f, 0.f, 0.f};

#pragma unroll
        for (int ks = 0; ks < 2; ++ks) {
            short8 bfr[4];
            const int d0 = ks * 32 + lg * 8;
            const float* xp = x + ((size_t)(b * CC + d0)) * NN + n0 + lr * 4;
#pragma unroll
            for (int j = 0; j < 8; ++j) {
                const float4 v = *reinterpret_cast<const float4*>(xp + (size_t)j * NN);
                bfr[0][j] = f2bf(v.x);
                bfr[1][j] = f2bf(v.y);
                bfr[2][j] = f2bf(v.z);
                bfr[3][j] = f2bf(v.w);
            }
#pragma unroll
            for (int ct = 0; ct < 4; ++ct) {
#pragma unroll
                for (int ph = 0; ph < 4; ++ph)
                    acc[ph][ct] = mfma16(afr[ct][ks], bfr[ph], acc[ph][ct]);
            }
        }
        // store: row c, cols n0 + lr*4 + {0..3}  (non-temporal, ext-vector type)
#pragma unroll
        for (int ct = 0; ct < 4; ++ct) {
#pragma unroll
            for (int r = 0; r < 4; ++r) {
                const int c = ct * 16 + lg * 4 + r;
                const float o = offv[ct][r];
                f32x4 vs;
                vs[0] = g * (acc[0][ct][r] - o);
                vs[1] = g * (acc[1][ct][r] - o);
                vs[2] = g * (acc[2][ct][r] - o);
                vs[3] = g * (acc[3][ct][r] - o);
                __builtin_nontemporal_store(
                    vs, reinterpret_cast<f32x4*>(out + ((size_t)(b * CC + c)) * NN + n0 + lr * 4));
            }
        }
    }
}

extern "C" void kernel_launch(void* const* d_in, const int* in_sizes, int n_in,
                              void* d_out, int out_size, void* d_ws, size_t ws_size,
                              hipStream_t stream) {
    const float* x     = (const float*)d_in[0];
    const float* gamma = (const float*)d_in[1];
    float* out = (float*)d_out;

    // Large deterministic partials live at the FRONT of d_out (fully overwritten
    // by k3 afterwards). Only the small att/offs tables (read by k3) use d_ws.
    float* partialG = out;                                   // 8*128*4096 floats (16.8 MB)
    float* partialS = out + (size_t)BB * SPLIT1 * 4096;      // 8*128*64 floats
    float* Gsum     = partialS + BB * SPLIT1 * CC;           // 8*4096 floats
    float* offs     = (float*)d_ws;                          // 512 floats
    unsigned short* att = (unsigned short*)((char*)d_ws + 4096);  // 8*4096 bf16

    k1_gram<<<BB * SPLIT1, 256, 0, stream>>>(x, partialG, partialS);
    k2a_reduceG<<<(BB * 4096) / 256, 256, 0, stream>>>(partialG, Gsum);
    k2b_softmax<<<BB, 256, 0, stream>>>(partialS, Gsum, att, offs);
    k3_apply<<<BB * SPLIT3, 256, 0, stream>>>(x, att, offs, gamma, out);
}

// Round 6
// 84.239 us; speedup vs baseline: 1.5053x; 1.2772x over previous
//
#include <hip/hip_runtime.h>
#include <hip/hip_bf16.h>

typedef __attribute__((ext_vector_type(8))) short short8;
typedef __attribute__((ext_vector_type(4))) short short4v;
typedef __attribute__((ext_vector_type(4))) float f32x4;
typedef __attribute__((ext_vector_type(8))) __bf16 bf16x8;

#define BB 8
#define CC 64
#define NN 65536        // H*W = 256*256
#define SPLIT1 64       // k1 blocks per batch (512 total = 2 blocks/CU; LDS caps at 2 anyway)
#define COLS1 (NN / SPLIT1)   // 1024 cols per k1 block
#define TILE_C 128            // fp32 tile cols: 64 x 128 x 4B = 32 KB per buffer
#define NT1 (COLS1 / TILE_C)  // 8 tiles per block
#define SPLIT3 128      // k3 blocks per batch (proven best in R3)

__device__ inline short f2bf(float f) {
    __hip_bfloat16 h = __float2bfloat16(f);
    return __builtin_bit_cast(short, h);
}

// --- MFMA wrapper: tolerate either short8 or bf16x8 builtin signature ---
template <typename V>
__device__ inline auto mfma_bf16_impl(V a, V b, f32x4 c, int)
    -> decltype(__builtin_amdgcn_mfma_f32_16x16x32_bf16(a, b, c, 0, 0, 0)) {
    return __builtin_amdgcn_mfma_f32_16x16x32_bf16(a, b, c, 0, 0, 0);
}
template <typename V>
__device__ inline f32x4 mfma_bf16_impl(V a, V b, f32x4 c, long) {
    bf16x8 a2 = __builtin_bit_cast(bf16x8, a);
    bf16x8 b2 = __builtin_bit_cast(bf16x8, b);
    return __builtin_amdgcn_mfma_f32_16x16x32_bf16(a2, b2, c, 0, 0, 0);
}
__device__ inline f32x4 mfma16(short8 a, short8 b, f32x4 c) {
    return mfma_bf16_impl(a, b, c, 0);
}

// ---- async global->LDS staging of one 64x128 fp32 tile -----------------------
// LDS dest is LINEAR (wave-uniform base + lane*16 -- HW requirement); the XOR
// swizzle ((row&31)<<4 on the in-row byte offset) is applied to the GLOBAL
// source address instead, so swizzled reads see consistent data (rule #21).
__device__ inline void stage_tile(const float* __restrict__ xb, int colbase,
                                  float* buf, int tid) {
    const int half = tid >> 5;   // two rows per 64-lane wave
    const int sl   = tid & 31;   // 16-B slot within the 512-B row
#pragma unroll
    for (int i = 0; i < 8; ++i) {
        const int row   = i * 8 + half;                 // 0..63
        const int gbyte = (sl * 16) ^ ((row & 31) << 4); // pre-swizzled source
        const float* gp = xb + (size_t)row * NN + colbase + (gbyte >> 2);
        float* lp = buf + i * 1024 + tid * 4;            // linear LDS dest
#if __has_builtin(__builtin_amdgcn_global_load_lds)
        __builtin_amdgcn_global_load_lds(
            (const __attribute__((address_space(1))) void*)gp,
            (__attribute__((address_space(3))) void*)lp, 16, 0, 0);
#else
        *reinterpret_cast<f32x4*>(lp) = *reinterpret_cast<const f32x4*>(gp);
#endif
    }
}

// read 8 consecutive fp32 tile elements (row, cols c0..c0+7) through the swizzle
__device__ inline void lds_read8(const float* buf, int row, int c0, float* v) {
    const char* rb = (const char*)(buf + row * TILE_C);
    const int swz = (row & 31) << 4;
    const f32x4 u0 = *reinterpret_cast<const f32x4*>(rb + ((c0 * 4) ^ swz));
    const f32x4 u1 = *reinterpret_cast<const f32x4*>(rb + (((c0 * 4) + 16) ^ swz));
    v[0] = u0[0]; v[1] = u0[1]; v[2] = u0[2]; v[3] = u0[3];
    v[4] = u1[0]; v[5] = u1[1]; v[6] = u1[2]; v[7] = u1[3];
}

__device__ inline short8 cvt8(const float* v) {
    short8 r;
#pragma unroll
    for (int j = 0; j < 8; ++j) r[j] = f2bf(v[j]);
    return r;
}

// ------- Kernel 1: partial Gram (bf16 MFMA) + channel sums, async 2-phase ----
__global__ __launch_bounds__(256) void k1_gram(const float* __restrict__ x,
                                               float* __restrict__ partialG,
                                               float* __restrict__ partialS) {
    __shared__ float lbuf[2][CC * TILE_C];   // 2 x 32 KB
    const int blk  = blockIdx.x;
    const int b    = blk / SPLIT1;
    const int s    = blk % SPLIT1;
    const int tid  = threadIdx.x;
    const int w    = tid >> 6, lane = tid & 63, lg = lane >> 4, lr = lane & 15;
    const float* xb = x + (size_t)b * CC * NN;
    const int colbase0 = s * COLS1;

    f32x4 acc[4];
#pragma unroll
    for (int dt = 0; dt < 4; ++dt) acc[dt] = (f32x4){0.f, 0.f, 0.f, 0.f};
    float asum = 0.f;

    stage_tile(xb, colbase0, lbuf[0], tid);
    __syncthreads();   // compiler drains vmcnt before barrier

    for (int t = 0; t < NT1; ++t) {
        if (t + 1 < NT1)
            stage_tile(xb, colbase0 + (t + 1) * TILE_C, lbuf[(t + 1) & 1], tid);
        const float* buf = lbuf[t & 1];
#pragma unroll
        for (int kk = 0; kk < TILE_C / 32; ++kk) {
            const int c0 = kk * 32 + lg * 8;
            float av[8];
            lds_read8(buf, w * 16 + lr, c0, av);
#pragma unroll
            for (int j = 0; j < 8; ++j) asum += av[j];
            const short8 af = cvt8(av);
#pragma unroll
            for (int dt = 0; dt < 4; ++dt) {
                float bv[8];
                lds_read8(buf, dt * 16 + lr, c0, bv);
                const short8 bf = cvt8(bv);
                acc[dt] = mfma16(af, bf, acc[dt]);
            }
        }
        __syncthreads();
    }
    // ---- write partial Gram (C/D map: col=lane&15, row=(lane>>4)*4+reg) ----
#pragma unroll
    for (int dt = 0; dt < 4; ++dt) {
#pragma unroll
        for (int r = 0; r < 4; ++r) {
            const int c = w * 16 + lg * 4 + r;
            const int d = dt * 16 + lr;
            partialG[(size_t)blk * 4096 + c * 64 + d] = acc[dt][r];
        }
    }
    // ---- channel sums: lane (lg,lr) holds the lg-quarter of row w*16+lr ----
    float v = asum;
    v += __shfl_xor(v, 16);
    v += __shfl_xor(v, 32);
    if (lg == 0) partialS[blk * CC + w * 16 + lr] = v;
}

// ---------------- Kernel 2a: reduce partial Gram over splits ----------------
__global__ __launch_bounds__(256) void k2a_reduceG(const float* __restrict__ partialG,
                                                   float* __restrict__ Gsum) {
    const int gid = blockIdx.x * 256 + threadIdx.x;   // 0..32767
    const int b = gid >> 12;
    const int e = gid & 4095;
    float s = 0.f;
    for (int sp = 0; sp < SPLIT1; ++sp)
        s += partialG[(((size_t)(b * SPLIT1 + sp)) << 12) + e];
    Gsum[gid] = s;
}

// ------- Kernel 2b: means, energy, softmax -> att(bf16) + offsets -----------
__global__ __launch_bounds__(256) void k2b_softmax(const float* __restrict__ partialS,
                                                   const float* __restrict__ Gsum,
                                                   unsigned short* __restrict__ att,
                                                   float* __restrict__ offs) {
    __shared__ float mu[CC];
    __shared__ float ener[CC * CC];
    const int b = blockIdx.x;
    const int tid = threadIdx.x;
    if (tid < CC) {
        float s = 0.f;
        for (int sp = 0; sp < SPLIT1; ++sp) s += partialS[(b * SPLIT1 + sp) * CC + tid];
        mu[tid] = s * (1.f / NN);
    }
    __syncthreads();
    const float inv_n = 1.f / NN;
#pragma unroll
    for (int k = 0; k < 16; ++k) {
        const int e = tid + k * 256;
        const int c = e >> 6, d = e & 63;
        ener[e] = Gsum[(b << 12) + e] * inv_n - mu[c] * mu[d];
    }
    __syncthreads();
    const int w = tid >> 6, lane = tid & 63;
    for (int i = 0; i < 16; ++i) {
        const int c = w * 16 + i;
        const float v = ener[c * 64 + lane];
        float m = v;
        for (int off = 32; off > 0; off >>= 1) m = fmaxf(m, __shfl_xor(m, off));
        const float ev = __expf(v - m);
        float sum = ev;
        for (int off = 32; off > 0; off >>= 1) sum += __shfl_xor(sum, off);
        const float a = ev / sum;
        att[(b << 12) + c * 64 + lane] = (unsigned short)f2bf(a);
        float o = a * mu[lane];
        for (int off = 32; off > 0; off >>= 1) o += __shfl_xor(o, off);
        if (lane == 0) offs[b * CC + c] = o;
    }
}

// ---------------- Kernel 3: out = gamma * (A @ x - offset) ------------------
// Non-temporal stores keep x resident in Infinity Cache (134 MB < 256 MB L3).
__global__ __launch_bounds__(256) void k3_apply(const float* __restrict__ x,
                                                const unsigned short* __restrict__ att,
                                                const float* __restrict__ offs,
                                                const float* __restrict__ gamma,
                                                float* __restrict__ out) {
    const int blk  = blockIdx.x;
    const int b    = blk / SPLIT3;
    const int s    = blk % SPLIT3;
    const int tid  = threadIdx.x;
    const int w    = tid >> 6, lane = tid & 63, lg = lane >> 4, lr = lane & 15;
    const float g  = gamma[0];

    // preload attention A-fragments
    short8 afr[4][2];
#pragma unroll
    for (int ct = 0; ct < 4; ++ct)
#pragma unroll
        for (int ks = 0; ks < 2; ++ks)
            afr[ct][ks] = *reinterpret_cast<const short8*>(
                att + (((size_t)b) << 12) + (ct * 16 + lr) * 64 + ks * 32 + lg * 8);

    float offv[4][4];
#pragma unroll
    for (int ct = 0; ct < 4; ++ct)
#pragma unroll
        for (int r = 0; r < 4; ++r)
            offv[ct][r] = offs[b * CC + ct * 16 + lg * 4 + r];

    const int colblock = s * (NN / SPLIT3);
    const int GROUPS = (NN / SPLIT3) / (4 * 64);   // 64-col groups per wave (=2)
    for (int itg = 0; itg < GROUPS; ++itg) {
        const int n0 = colblock + (w * GROUPS + itg) * 64;
        f32x4 acc[4][4];   // [phase][ct]
#pragma unroll
        for (int ph = 0; ph < 4; ++ph)
#pragma unroll
            for (int ct = 0; ct < 4; ++ct) acc[ph][ct] = (f32x4){0.f, 0.f, 0.f, 0.f};

#pragma unroll
        for (int ks = 0; ks < 2; ++ks) {
            short8 bfr[4];
            const int d0 = ks * 32 + lg * 8;
            const float* xp = x + ((size_t)(b * CC + d0)) * NN + n0 + lr * 4;
#pragma unroll
            for (int j = 0; j < 8; ++j) {
                const float4 v = *reinterpret_cast<const float4*>(xp + (size_t)j * NN);
                bfr[0][j] = f2bf(v.x);
                bfr[1][j] = f2bf(v.y);
                bfr[2][j] = f2bf(v.z);
                bfr[3][j] = f2bf(v.w);
            }
#pragma unroll
            for (int ct = 0; ct < 4; ++ct) {
#pragma unroll
                for (int ph = 0; ph < 4; ++ph)
                    acc[ph][ct] = mfma16(afr[ct][ks], bfr[ph], acc[ph][ct]);
            }
        }
        // store: row c, cols n0 + lr*4 + {0..3}  (non-temporal)
#pragma unroll
        for (int ct = 0; ct < 4; ++ct) {
#pragma unroll
            for (int r = 0; r < 4; ++r) {
                const int c = ct * 16 + lg * 4 + r;
                const float o = offv[ct][r];
                f32x4 vs;
                vs[0] = g * (acc[0][ct][r] - o);
                vs[1] = g * (acc[1][ct][r] - o);
                vs[2] = g * (acc[2][ct][r] - o);
                vs[3] = g * (acc[3][ct][r] - o);
                __builtin_nontemporal_store(
                    vs, reinterpret_cast<f32x4*>(out + ((size_t)(b * CC + c)) * NN + n0 + lr * 4));
            }
        }
    }
}

extern "C" void kernel_launch(void* const* d_in, const int* in_sizes, int n_in,
                              void* d_out, int out_size, void* d_ws, size_t ws_size,
                              hipStream_t stream) {
    const float* x     = (const float*)d_in[0];
    const float* gamma = (const float*)d_in[1];
    float* out = (float*)d_out;

    // Large deterministic partials live at the FRONT of d_out (fully overwritten
    // by k3 afterwards). Only the small att/offs tables (read by k3) use d_ws.
    float* partialG = out;                                   // 8*64*4096 floats (8.4 MB)
    float* partialS = out + (size_t)BB * SPLIT1 * 4096;      // 8*64*64 floats
    float* Gsum     = partialS + BB * SPLIT1 * CC;           // 8*4096 floats
    float* offs     = (float*)d_ws;                          // 512 floats
    unsigned short* att = (unsigned short*)((char*)d_ws + 4096);  // 8*4096 bf16

    k1_gram<<<BB * SPLIT1, 256, 0, stream>>>(x, partialG, partialS);
    k2a_reduceG<<<(BB * 4096) / 256, 256, 0, stream>>>(partialG, Gsum);
    k2b_softmax<<<BB, 256, 0, stream>>>(partialS, Gsum, att, offs);
    k3_apply<<<BB * SPLIT3, 256, 0, stream>>>(x, att, offs, gamma, out);
}